// Round 11
// baseline (319.362 us; speedup 1.0000x reference)
//
#include <hip/hip_runtime.h>
#include <stdint.h>

#define T_TOKENS 2048
#define DM 1024
#define DF 4096
#define NEXP 8
#define NSLOTS (T_TOKENS * 2)
#define HROWS (NSLOTS + 256)   // slack for unguarded tail A-reads (256-row tiles)

typedef __bf16 bf16x8 __attribute__((ext_vector_type(8)));
typedef float f32x4 __attribute__((ext_vector_type(4)));

__device__ __forceinline__ ushort f2bf(float f) {
    union { float f; uint32_t u; } v; v.f = f;
    uint32_t r = v.u + 0x7FFFu + ((v.u >> 16) & 1u);
    return (ushort)(r >> 16);
}

__device__ __forceinline__ void gload16(const ushort* g, ushort* l) {
    __builtin_amdgcn_global_load_lds(
        (const __attribute__((address_space(1))) uint32_t*)g,
        (__attribute__((address_space(3))) uint32_t*)l,
        16, 0, 0);
}

// ---------------- init: zero expert counters ----------------
__global__ void init_cnt(uint32_t* cnt) {
    if (threadIdx.x < NEXP) cnt[threadIdx.x] = 0;
}

// ---------------- gating + routing: one wave per token ----------------
__global__ __launch_bounds__(256) void gate_route(
    const float* __restrict__ x, const float* __restrict__ gw,
    const float* __restrict__ gb,
    uint32_t* __restrict__ route, uint32_t* __restrict__ cnt,
    float* __restrict__ prob, uint32_t* __restrict__ epk)
{
    const int w = threadIdx.x >> 6;
    const int lane = threadIdx.x & 63;
    const int t = blockIdx.x * 4 + w;
    float acc[NEXP];
#pragma unroll
    for (int e = 0; e < NEXP; ++e) acc[e] = 0.f;
    const float* xr = x + (size_t)t * DM;
#pragma unroll
    for (int j = 0; j < DM / 64; ++j) {
        const int d = j * 64 + lane;
        const float xv = xr[d];
        const float* g = gw + (size_t)d * NEXP;
#pragma unroll
        for (int e = 0; e < NEXP; ++e) acc[e] += xv * g[e];
    }
#pragma unroll
    for (int e = 0; e < NEXP; ++e) {
#pragma unroll
        for (int off = 32; off > 0; off >>= 1)
            acc[e] += __shfl_xor(acc[e], off);
        acc[e] += gb[e];
    }
    if (lane == 0) {
        int e0 = 0; float v0 = acc[0];
#pragma unroll
        for (int e = 1; e < NEXP; ++e) if (acc[e] > v0) { v0 = acc[e]; e0 = e; }
        int e1 = -1; float v1 = -1e30f;
#pragma unroll
        for (int e = 0; e < NEXP; ++e) if (e != e0 && acc[e] > v1) { v1 = acc[e]; e1 = e; }
        const float ex = expf(v1 - v0);
        const float inv = 1.f / (1.f + ex);
        prob[t * 2 + 0] = inv;
        prob[t * 2 + 1] = ex * inv;
        uint32_t pos = atomicAdd(&cnt[e0], 1u);
        route[e0 * T_TOKENS + pos] = (uint32_t)(t * 2);
        epk[t * 2] = ((uint32_t)e0 << 16) | pos;
        pos = atomicAdd(&cnt[e1], 1u);
        route[e1 * T_TOKENS + pos] = (uint32_t)(t * 2 + 1);
        epk[t * 2 + 1] = ((uint32_t)e1 << 16) | pos;
    }
}

// ---------------- exclusive prefix over the 8 counts ----------------
__global__ void prefix_offs(const uint32_t* __restrict__ cnt,
                            uint32_t* __restrict__ offs)
{
    if (threadIdx.x == 0) {
        uint32_t a = 0;
#pragma unroll
        for (int e = 0; e < NEXP; ++e) { offs[e] = a; a += cnt[e]; }
        offs[NEXP] = a;
    }
}

// ---------------- x fp32 -> bf16 ----------------
__global__ __launch_bounds__(256) void convert_x(const float* __restrict__ x,
                                                 ushort* __restrict__ xb)
{
    const int i = (blockIdx.x * 256 + threadIdx.x) * 4;
    const float4 v = *reinterpret_cast<const float4*>(x + i);
    ushort4 o;
    o.x = f2bf(v.x); o.y = f2bf(v.y); o.z = f2bf(v.z); o.w = f2bf(v.w);
    *reinterpret_cast<ushort4*>(xb + i) = o;
}

// ---------------- W [E][K][N] f32 -> Wb [E][N][K] bf16 (64x64 tiles) ----------
template<int K, int N>
__global__ __launch_bounds__(256) void conv_transpose(const float* __restrict__ W,
                                                      ushort* __restrict__ Wb)
{
    const int e  = blockIdx.y;
    const int nt = blockIdx.x % (N / 64);
    const int kt = blockIdx.x / (N / 64);
    const int k0 = kt * 64, n0 = nt * 64;
    __shared__ ushort T[64][80];
    const int t = threadIdx.x;
    const int kr = t >> 4, nc = (t & 15) * 4;
    const float* src = W + ((size_t)e * K + k0 + kr) * N + n0 + nc;
#pragma unroll
    for (int i = 0; i < 4; ++i) {
        const float4 v = *reinterpret_cast<const float4*>(src + (size_t)i * 16 * N);
        T[nc + 0][kr + i * 16] = f2bf(v.x);
        T[nc + 1][kr + i * 16] = f2bf(v.y);
        T[nc + 2][kr + i * 16] = f2bf(v.z);
        T[nc + 3][kr + i * 16] = f2bf(v.w);
    }
    __syncthreads();
    const int r = t >> 2, c0 = t & 3;
    ushort* dst = Wb + ((size_t)e * N + n0 + r) * K + k0;
#pragma unroll
    for (int i = 0; i < 2; ++i) {
        const int c = c0 + i * 4;
        const uint4 v = *reinterpret_cast<const uint4*>(&T[r][c * 8]);
        *reinterpret_cast<uint4*>(dst + c * 8) = v;
    }
}

// --- grouped expert GEMM v11: R9 (256x256, BK=64, vmcnt(8)) + XCD swizzle ----
// Inner loop IDENTICAL to R9's moe_gemm9 (correctness-verified): 8 waves
// (2Mx4N), per-wave 128x64, 128B-row chunk-XOR swizzle cs=c^(row&7)
// (involution on staging source + fragment read; 0 conflicts, R9), counted
// vmcnt(8) 2-phase double buffer.
// NEW (from R10, +5x FETCH win): bijective XCD-chunked blockIdx swizzle,
// decode e -> nt -> mt (mt fastest). cpx = work/8; each XCD owns exactly one
// expert, so its A rows and B panels stay L2/L3-local.
template<int KD, int ND, bool FIRST, int SPLIT, int NMT, int NT>
__global__ __launch_bounds__(512, 2) void moe_gemm11(
    const ushort* __restrict__ Abuf,
    const ushort* __restrict__ Wb,
    const float* __restrict__ bias,
    const uint32_t* __restrict__ route,
    const uint32_t* __restrict__ cnt,
    const uint32_t* __restrict__ offs,
    const float* __restrict__ prob,
    ushort* __restrict__ hout,
    float* __restrict__ yout)
{
    // XCD-chunked bijective swizzle: work = (bx%8)*cpx + bx/8
    const int bx0 = blockIdx.x;
    const int cpx = (NEXP * NMT * NT) >> 3;
    const int wk  = (bx0 & 7) * cpx + (bx0 >> 3);
    const int e   = wk / (NMT * NT);
    const int r   = wk % (NMT * NT);
    const int nt  = r / NMT;
    const int mt  = r % NMT;          // mt fastest: B panel shared by adjacent work
    const uint32_t cntE = cnt[e];
    const int m0 = mt * 256;
    if ((uint32_t)m0 >= cntE) return;
    const uint32_t hb = offs[e];
    const int n0 = nt * 256;
    const int z  = (SPLIT > 1) ? (int)blockIdx.z : 0;
    const int kbeg = z * (KD / SPLIT);
    const int niter = (KD / SPLIT) / 64;

    __shared__ ushort As[2][256 * 64];   // 64 KB
    __shared__ ushort Bs[2][256 * 64];   // 64 KB
    __shared__ uint32_t s_route[256];
    __shared__ float s_p[256];

    const int tid = threadIdx.x;
    if (FIRST) {
        if (tid < 256) {
            const uint32_t idx = (uint32_t)(m0 + tid);
            const uint32_t s = (idx < cntE) ? route[e * T_TOKENS + idx] : 0u;
            s_route[tid] = s;
            s_p[tid] = prob[s];
        }
        __syncthreads();
    }

    const int w = tid >> 6, l = tid & 63;

    // staging: 4 A-chunks + 4 B-chunks (16B) per thread (8 loads/iter).
    // Tile = 256 rows x 128B = 2048 chunks. LDS dest linear (chunk*16B);
    // global source carries the inverse swizzle: row = 8 chunks; LDS chunk c
    // holds global chunk c ^ (row&7).
    const ushort* asrc[4];
    const ushort* bsrc[4];
#pragma unroll
    for (int i = 0; i < 4; ++i) {
        const int chunk = (w * 4 + i) * 64 + l;   // 0..2047
        const int row = chunk >> 3;               // 0..255
        const int c   = chunk & 7;
        const int cs  = c ^ (row & 7);
        size_t arow;
        if (FIRST) arow = (size_t)(s_route[row] >> 1);     // token id
        else       arow = (size_t)(hb + m0 + row);         // expert-order h row
        asrc[i] = Abuf + arow * KD + cs * 8 + kbeg;
        bsrc[i] = Wb + ((size_t)e * ND + n0 + row) * KD + cs * 8 + kbeg;
    }

    f32x4 acc[8][4];
#pragma unroll
    for (int i = 0; i < 8; ++i)
#pragma unroll
        for (int j = 0; j < 4; ++j) acc[i][j] = (f32x4){0.f, 0.f, 0.f, 0.f};

    const int q = l & 15, g = l >> 4;
    const int wm = w >> 2, wn = w & 3;        // 2M x 4N wave grid

    // swizzled fragment byte offsets within a [256][64] bf16 buffer
    int aoff[8][2], boff[4][2];
#pragma unroll
    for (int mi = 0; mi < 8; ++mi) {
        const int row = wm * 128 + mi * 16 + q;
#pragma unroll
        for (int ks = 0; ks < 2; ++ks)
            aoff[mi][ks] = row * 128 + (((ks * 4 + g) ^ (row & 7)) * 16);
    }
#pragma unroll
    for (int ni = 0; ni < 4; ++ni) {
        const int row = wn * 64 + ni * 16 + q;
#pragma unroll
        for (int ks = 0; ks < 2; ++ks)
            boff[ni][ks] = row * 128 + (((ks * 4 + g) ^ (row & 7)) * 16);
    }

    ushort* const abase0 = &As[0][0];
    ushort* const bbase0 = &Bs[0][0];

    // prologue: stage tile 0 into buf 0 (8 loads in flight per thread)
#pragma unroll
    for (int i = 0; i < 4; ++i) gload16(asrc[i], abase0 + (w * 4 + i) * 512);
#pragma unroll
    for (int i = 0; i < 4; ++i) gload16(bsrc[i], bbase0 + (w * 4 + i) * 512);

    int cur = 0;
#pragma unroll 1
    for (int t = 0; t < niter; ++t) {
        // issue next-tile prefetch, then wait only for tile t's 8 loads
        if (t + 1 < niter) {
            ushort* ad = abase0 + (cur ^ 1) * (256 * 64) + (w * 4) * 512;
            ushort* bd = bbase0 + (cur ^ 1) * (256 * 64) + (w * 4) * 512;
            const int k1 = (t + 1) * 64;
#pragma unroll
            for (int i = 0; i < 4; ++i) gload16(asrc[i] + k1, ad + i * 512);
#pragma unroll
            for (int i = 0; i < 4; ++i) gload16(bsrc[i] + k1, bd + i * 512);
            asm volatile("s_waitcnt vmcnt(8)" ::: "memory");
        } else {
            asm volatile("s_waitcnt vmcnt(0)" ::: "memory");
        }
        __builtin_amdgcn_s_barrier();
        __builtin_amdgcn_sched_barrier(0);

        // compute current tile: 2 k-halves x 32 MFMA
        const char* Ab = (const char*)(abase0 + cur * (256 * 64));
        const char* Bb = (const char*)(bbase0 + cur * (256 * 64));
#pragma unroll
        for (int ks = 0; ks < 2; ++ks) {
            bf16x8 af[8], bv[4];
#pragma unroll
            for (int ni = 0; ni < 4; ++ni)
                bv[ni] = *reinterpret_cast<const bf16x8*>(Bb + boff[ni][ks]);
#pragma unroll
            for (int mi = 0; mi < 8; ++mi)
                af[mi] = *reinterpret_cast<const bf16x8*>(Ab + aoff[mi][ks]);
            __builtin_amdgcn_s_setprio(1);
#pragma unroll
            for (int mi = 0; mi < 8; ++mi)
#pragma unroll
                for (int ni = 0; ni < 4; ++ni)
                    acc[mi][ni] = __builtin_amdgcn_mfma_f32_16x16x32_bf16(
                        af[mi], bv[ni], acc[mi][ni], 0, 0, 0);
            __builtin_amdgcn_s_setprio(0);
        }
        // all waves done reading buf[cur] before next iteration overwrites it
        __builtin_amdgcn_s_barrier();
        cur ^= 1;
    }

    // epilogue
#pragma unroll
    for (int mi = 0; mi < 8; ++mi) {
#pragma unroll
        for (int ni = 0; ni < 4; ++ni) {
            const int gcol = n0 + wn * 64 + ni * 16 + q;
            float bvx = 0.f;
            if (FIRST) bvx = bias[e * ND + gcol];
#pragma unroll
            for (int j = 0; j < 4; ++j) {
                const int row = wm * 128 + mi * 16 + g * 4 + j;
                if ((uint32_t)(m0 + row) < cntE) {
                    const size_t grow = (size_t)(hb + m0 + row);
                    if (FIRST) {
                        float v = acc[mi][ni][j] + bvx;
                        v = fmaxf(v, 0.f) * s_p[row];
                        hout[grow * ND + gcol] = f2bf(v);
                    } else {
                        yout[((size_t)z * NSLOTS + grow) * ND + gcol] = acc[mi][ni][j];
                    }
                }
            }
        }
    }
}

// ------- combine: out[t] = p0*b2[e0] + p1*b2[e1] + sum_z (yc[z][r0]+yc[z][r1])
__global__ __launch_bounds__(256) void combine5(
    const float* __restrict__ yc, const uint32_t* __restrict__ epk,
    const uint32_t* __restrict__ offs, const float* __restrict__ prob,
    const float* __restrict__ b2, float* __restrict__ out)
{
    const int gid = blockIdx.x * 256 + threadIdx.x;   // over T*DM/4
    const int t = gid >> 8;
    const int dq = gid & 255;
    const uint32_t p0 = epk[2 * t], p1 = epk[2 * t + 1];
    const uint32_t e0 = p0 >> 16, e1 = p1 >> 16;
    const uint32_t r0 = offs[e0] + (p0 & 0xFFFFu);
    const uint32_t r1 = offs[e1] + (p1 & 0xFFFFu);
    const float w0 = prob[2 * t], w1 = prob[2 * t + 1];
    const float4 bb0 = reinterpret_cast<const float4*>(b2 + (size_t)e0 * DM)[dq];
    const float4 bb1 = reinterpret_cast<const float4*>(b2 + (size_t)e1 * DM)[dq];
    float4 o = { w0 * bb0.x + w1 * bb1.x, w0 * bb0.y + w1 * bb1.y,
                 w0 * bb0.z + w1 * bb1.z, w0 * bb0.w + w1 * bb1.w };
    const float4* Y = reinterpret_cast<const float4*>(yc);
#pragma unroll
    for (int zz = 0; zz < 4; ++zz) {
        const float4 a = Y[((size_t)zz * NSLOTS + r0) * 256 + dq];
        const float4 b = Y[((size_t)zz * NSLOTS + r1) * 256 + dq];
        o.x += a.x + b.x; o.y += a.y + b.y; o.z += a.z + b.z; o.w += a.w + b.w;
    }
    reinterpret_cast<float4*>(out)[gid] = o;
}

// ================= fallback path (round-1, works in ~55 MB ws) =================
template<int KD, int ND, bool FIRST>
__global__ __launch_bounds__(256) void moe_gemm_v1(
    const ushort* __restrict__ Abuf, const float* __restrict__ W,
    const float* __restrict__ bias, const uint32_t* __restrict__ route,
    const uint32_t* __restrict__ cnt, const float* __restrict__ prob,
    ushort* __restrict__ hout, float* __restrict__ yout)
{
    const int e = blockIdx.x >> 4;
    const int mt = blockIdx.x & 15;
    const uint32_t cntE = cnt[e];
    const int m0 = mt * 128;
    if ((uint32_t)m0 >= cntE) return;
    const int n0 = blockIdx.y * 128;
    const int tid = threadIdx.x;
    __shared__ ushort Asm[128][40];
    __shared__ ushort Bsm[128][40];
    __shared__ uint32_t s_route[128];
    if (tid < 128) {
        const uint32_t idx = (uint32_t)(m0 + tid);
        s_route[tid] = (idx < cntE) ? route[e * T_TOKENS + idx] : 0xFFFFFFFFu;
    }
    __syncthreads();
    const int ar = tid >> 1, ah = tid & 1;
    const uint32_t s_a = s_route[ar];
    size_t arow = 0;
    if (s_a != 0xFFFFFFFFu) arow = FIRST ? (size_t)(s_a >> 1) : (size_t)s_a;
    const ushort* asrc = Abuf + arow * KD + ah * 16;
    const int c4 = tid & 31, kq = tid >> 5;
    const float* wbase = W + (size_t)e * KD * ND + (size_t)n0 + (size_t)c4 * 4;
    f32x4 acc[4][4];
#pragma unroll
    for (int i = 0; i < 4; ++i)
#pragma unroll
        for (int j = 0; j < 4; ++j) acc[i][j] = (f32x4){0.f, 0.f, 0.f, 0.f};
    const int lane = tid & 63, wv = tid >> 6;
    const int wm = wv >> 1, wn = wv & 1;
    const int q = lane & 15, g = lane >> 4;
    for (int k0 = 0; k0 < KD; k0 += 32) {
        {
            const uint4* src = reinterpret_cast<const uint4*>(asrc + k0);
            const uint4 v0 = src[0];
            const uint4 v1 = src[1];
            *reinterpret_cast<uint4*>(&Asm[ar][ah * 16]) = v0;
            *reinterpret_cast<uint4*>(&Asm[ar][ah * 16 + 8]) = v1;
        }
        {
            ushort vals[4][4];
#pragma unroll
            for (int r = 0; r < 4; ++r) {
                const float4 v = *reinterpret_cast<const float4*>(
                    wbase + (size_t)(k0 + kq * 4 + r) * ND);
                vals[r][0] = f2bf(v.x); vals[r][1] = f2bf(v.y);
                vals[r][2] = f2bf(v.z); vals[r][3] = f2bf(v.w);
            }
#pragma unroll
            for (int c = 0; c < 4; ++c) {
                const ushort4 o = { vals[0][c], vals[1][c], vals[2][c], vals[3][c] };
                *reinterpret_cast<ushort4*>(&Bsm[c4 * 4 + c][kq * 4]) = o;
            }
        }
        __syncthreads();
        bf16x8 af[4], bfr[4];
#pragma unroll
        for (int mi = 0; mi < 4; ++mi)
            af[mi] = *reinterpret_cast<const bf16x8*>(&Asm[wm * 64 + mi * 16 + q][g * 8]);
#pragma unroll
        for (int ni = 0; ni < 4; ++ni)
            bfr[ni] = *reinterpret_cast<const bf16x8*>(&Bsm[wn * 64 + ni * 16 + q][g * 8]);
#pragma unroll
        for (int mi = 0; mi < 4; ++mi)
#pragma unroll
            for (int ni = 0; ni < 4; ++ni)
                acc[mi][ni] = __builtin_amdgcn_mfma_f32_16x16x32_bf16(
                    af[mi], bfr[ni], acc[mi][ni], 0, 0, 0);
        __syncthreads();
    }
#pragma unroll
    for (int mi = 0; mi < 4; ++mi) {
#pragma unroll
        for (int ni = 0; ni < 4; ++ni) {
            const int gcol = n0 + wn * 64 + ni * 16 + q;
#pragma unroll
            for (int j = 0; j < 4; ++j) {
                const int row = wm * 64 + mi * 16 + g * 4 + j;
                if ((uint32_t)(m0 + row) < cntE) {
                    const uint32_t s = s_route[row];
                    float v = acc[mi][ni][j] + bias[e * ND + gcol];
                    if (FIRST) {
                        v = fmaxf(v, 0.f);
                        hout[(size_t)s * ND + gcol] = f2bf(v);
                    } else {
                        yout[(size_t)s * ND + gcol] = v * prob[s];
                    }
                }
            }
        }
    }
}

__global__ __launch_bounds__(256) void combine1(const float* __restrict__ yc,
                                                float* __restrict__ out)
{
    const int gid = blockIdx.x * 256 + threadIdx.x;
    const int t = gid >> 8;
    const int dq = gid & 255;
    const float4 va = reinterpret_cast<const float4*>(yc)[(size_t)(2 * t) * 256 + dq];
    const float4 vb = reinterpret_cast<const float4*>(yc)[(size_t)(2 * t + 1) * 256 + dq];
    const float4 o = { va.x + vb.x, va.y + vb.y, va.z + vb.z, va.w + vb.w };
    reinterpret_cast<float4*>(out)[gid] = o;
}

// ---------------- launch ----------------
extern "C" void kernel_launch(void* const* d_in, const int* in_sizes, int n_in,
                              void* d_out, int out_size, void* d_ws, size_t ws_size,
                              hipStream_t stream)
{
    const float* x  = (const float*)d_in[0];
    const float* gw = (const float*)d_in[1];
    const float* gb = (const float*)d_in[2];
    const float* W1 = (const float*)d_in[3];
    const float* b1 = (const float*)d_in[4];
    const float* W2 = (const float*)d_in[5];
    const float* b2 = (const float*)d_in[6];
    float* out = (float*)d_out;
    char* ws = (char*)d_ws;

    // ---- big layout (~168 MB; yc aliases w1b which is dead after GEMM1) ----
    const size_t OFF_XB    = 0;                        // 4 MiB
    const size_t OFF_H     = 4194304;                  // HROWS*4096*2 = 35.7 MB
    const size_t OFF_ROUTE = 39845888;                 // 64 KiB
    const size_t OFF_CNT   = 39911424;                 // 64 B
    const size_t OFF_OFFS  = 39911488;                 // 64 B
    const size_t OFF_PROB  = 39911552;                 // 16 KiB
    const size_t OFF_EPK   = 39927936;                 // 16 KiB
    const size_t OFF_W1B   = 41943040;                 // 64 MiB (aliased by yc)
    const size_t OFF_W2B   = 109051904;                // 64 MiB
    const size_t OFF_YC    = OFF_W1B;                  // 64 MiB (4 z-splits)
    const size_t NEED      = 176160768ull;

    if (ws_size >= NEED) {
        ushort*   xb    = (ushort*)(ws + OFF_XB);
        ushort*   h     = (ushort*)(ws + OFF_H);
        float*    yc    = (float*)(ws + OFF_YC);
        uint32_t* route = (uint32_t*)(ws + OFF_ROUTE);
        uint32_t* cnt   = (uint32_t*)(ws + OFF_CNT);
        uint32_t* offs  = (uint32_t*)(ws + OFF_OFFS);
        float*    prob  = (float*)(ws + OFF_PROB);
        uint32_t* epk   = (uint32_t*)(ws + OFF_EPK);
        ushort*   w1b   = (ushort*)(ws + OFF_W1B);
        ushort*   w2b   = (ushort*)(ws + OFF_W2B);

        hipLaunchKernelGGL(init_cnt, dim3(1), dim3(64), 0, stream, cnt);
        hipLaunchKernelGGL(gate_route, dim3(T_TOKENS / 4), dim3(256), 0, stream,
                           x, gw, gb, route, cnt, prob, epk);
        hipLaunchKernelGGL(prefix_offs, dim3(1), dim3(64), 0, stream, cnt, offs);
        hipLaunchKernelGGL(convert_x, dim3(T_TOKENS * DM / 1024), dim3(256), 0, stream, x, xb);
        // W1 transpose right before GEMM1 (w1b + xb stay L3-hot)
        hipLaunchKernelGGL((conv_transpose<DM, DF>), dim3((DM / 64) * (DF / 64), NEXP),
                           dim3(256), 0, stream, W1, w1b);
        // GEMM1: 256x256, BK=64, NMT=8, NT=16 -> nwg=1024, cpx=128 (expert/XCD)
        hipLaunchKernelGGL((moe_gemm11<DM, DF, true, 1, 8, 16>),
                           dim3(NEXP * 8 * 16, 1, 1), dim3(512), 0, stream,
                           xb, w1b, b1, route, cnt, offs, prob, h, (float*)nullptr);
        // W2 transpose right before GEMM2; yc aliases w1b (dead now)
        hipLaunchKernelGGL((conv_transpose<DF, DM>), dim3((DF / 64) * (DM / 64), NEXP),
                           dim3(256), 0, stream, W2, w2b);
        // GEMM2: 256x256, BK=64, split-K=4, NMT=8, NT=4 -> nwg.x=256, cpx=32
        hipLaunchKernelGGL((moe_gemm11<DF, DM, false, 4, 8, 4>),
                           dim3(NEXP * 8 * 4, 1, 4), dim3(512), 0, stream,
                           h, w2b, (const float*)nullptr, route, cnt, offs,
                           (const float*)nullptr, (ushort*)nullptr, yc);
        hipLaunchKernelGGL(combine5, dim3(T_TOKENS * DM / 1024), dim3(256), 0, stream,
                           yc, epk, offs, prob, b2, out);
    } else {
        // ---- fallback: round-1 layout (~55 MB) ----
        const size_t F_XB = 0, F_H = 4194304, F_YC = 37748736;
        const size_t F_ROUTE = 54525952, F_CNT = 54591488, F_PROB = 54591552;
        ushort*   xb    = (ushort*)(ws + F_XB);
        ushort*   h     = (ushort*)(ws + F_H);
        float*    yc    = (float*)(ws + F_YC);
        uint32_t* route = (uint32_t*)(ws + F_ROUTE);
        uint32_t* cnt   = (uint32_t*)(ws + F_CNT);
        float*    prob  = (float*)(ws + F_PROB);
        uint32_t* epk   = (uint32_t*)(ws + F_PROB + 16384);

        hipLaunchKernelGGL(init_cnt, dim3(1), dim3(64), 0, stream, cnt);
        hipLaunchKernelGGL(gate_route, dim3(T_TOKENS / 4), dim3(256), 0, stream,
                           x, gw, gb, route, cnt, prob, epk);
        hipLaunchKernelGGL(convert_x, dim3(T_TOKENS * DM / 1024), dim3(256), 0, stream, x, xb);
        hipLaunchKernelGGL((moe_gemm_v1<DM, DF, true>), dim3(NEXP * 16, DF / 128),
                           dim3(256), 0, stream, xb, W1, b1, route, cnt, prob,
                           h, (float*)nullptr);
        hipLaunchKernelGGL((moe_gemm_v1<DF, DM, false>), dim3(NEXP * 16, DM / 128),
                           dim3(256), 0, stream, h, W2, b2, route, cnt, prob,
                           (ushort*)nullptr, yc);
        hipLaunchKernelGGL(combine1, dim3(T_TOKENS * DM / 1024), dim3(256), 0, stream, yc, out);
    }
}

// Round 12
// 285.943 us; speedup vs baseline: 1.1169x; 1.1169x over previous
//
#include <hip/hip_runtime.h>
#include <stdint.h>

#define T_TOKENS 2048
#define DM 1024
#define DF 4096
#define NEXP 8
#define NSLOTS (T_TOKENS * 2)

typedef __bf16 bf16x8 __attribute__((ext_vector_type(8)));
typedef float f32x4 __attribute__((ext_vector_type(4)));

__device__ __forceinline__ ushort f2bf(float f) {
    union { float f; uint32_t u; } v; v.f = f;
    uint32_t r = v.u + 0x7FFFu + ((v.u >> 16) & 1u);
    return (ushort)(r >> 16);
}

__device__ __forceinline__ void gload16(const ushort* g, ushort* l) {
    __builtin_amdgcn_global_load_lds(
        (const __attribute__((address_space(1))) uint32_t*)g,
        (__attribute__((address_space(3))) uint32_t*)l,
        16, 0, 0);
}

// ---------------- init: zero expert counters ----------------
__global__ void init_cnt(uint32_t* cnt) {
    if (threadIdx.x < NEXP) cnt[threadIdx.x] = 0;
}

// ---------------- exclusive prefix over the 8 counts ----------------
__global__ void prefix_offs(const uint32_t* __restrict__ cnt,
                            uint32_t* __restrict__ offs)
{
    if (threadIdx.x == 0) {
        uint32_t a = 0;
#pragma unroll
        for (int e = 0; e < NEXP; ++e) { offs[e] = a; a += cnt[e]; }
        offs[NEXP] = a;
    }
}

// ====== prep: gate_route [0,512) | convert_x [512,2560) | trW1 [2560,4608) ===
// All three phases are mutually independent; fusing overlaps trW1's 201 MB of
// BW work with gate's latency-bound reduction and saves 2 launch overheads.
__global__ __launch_bounds__(256) void prep_kernel(
    const float* __restrict__ x, const float* __restrict__ gw,
    const float* __restrict__ gb, const float* __restrict__ W1,
    uint32_t* __restrict__ route, uint32_t* __restrict__ cnt,
    float* __restrict__ prob, uint32_t* __restrict__ epk,
    ushort* __restrict__ xb, ushort* __restrict__ w1b)
{
    __shared__ ushort T[64][80];
    const int bx = blockIdx.x;
    const int tid = threadIdx.x;

    if (bx < 512) {
        // ---- gate + route: one wave per token ----
        const int w = tid >> 6;
        const int lane = tid & 63;
        const int t = bx * 4 + w;
        float acc[NEXP];
#pragma unroll
        for (int e = 0; e < NEXP; ++e) acc[e] = 0.f;
        const float* xr = x + (size_t)t * DM;
#pragma unroll
        for (int j = 0; j < DM / 64; ++j) {
            const int d = j * 64 + lane;
            const float xv = xr[d];
            const float* g = gw + (size_t)d * NEXP;
#pragma unroll
            for (int e = 0; e < NEXP; ++e) acc[e] += xv * g[e];
        }
#pragma unroll
        for (int e = 0; e < NEXP; ++e) {
#pragma unroll
            for (int off = 32; off > 0; off >>= 1)
                acc[e] += __shfl_xor(acc[e], off);
            acc[e] += gb[e];
        }
        if (lane == 0) {
            int e0 = 0; float v0 = acc[0];
#pragma unroll
            for (int e = 1; e < NEXP; ++e) if (acc[e] > v0) { v0 = acc[e]; e0 = e; }
            int e1 = -1; float v1 = -1e30f;
#pragma unroll
            for (int e = 0; e < NEXP; ++e) if (e != e0 && acc[e] > v1) { v1 = acc[e]; e1 = e; }
            const float ex = expf(v1 - v0);
            const float inv = 1.f / (1.f + ex);
            prob[t * 2 + 0] = inv;
            prob[t * 2 + 1] = ex * inv;
            uint32_t pos = atomicAdd(&cnt[e0], 1u);
            route[e0 * T_TOKENS + pos] = (uint32_t)(t * 2);
            epk[t * 2] = ((uint32_t)e0 << 16) | pos;
            pos = atomicAdd(&cnt[e1], 1u);
            route[e1 * T_TOKENS + pos] = (uint32_t)(t * 2 + 1);
            epk[t * 2 + 1] = ((uint32_t)e1 << 16) | pos;
        }
    } else if (bx < 2560) {
        // ---- x fp32 -> bf16 ----
        const int i = ((bx - 512) * 256 + tid) * 4;
        const float4 v = *reinterpret_cast<const float4*>(x + i);
        ushort4 o;
        o.x = f2bf(v.x); o.y = f2bf(v.y); o.z = f2bf(v.z); o.w = f2bf(v.w);
        *reinterpret_cast<ushort4*>(xb + i) = o;
    } else {
        // ---- W1 [E][DM][DF] f32 -> w1b [E][DF][DM] bf16 (4x 64x64 tiles) ----
        const int rel = bx - 2560;        // 0..2047
        const int e   = rel >> 8;         // 256 blocks/expert
        const int r   = rel & 255;
        const int nt  = r & 63;           // DF/64 = 64 n-tiles
        const int ktg = r >> 6;           // DM/256 = 4 k-groups
        const int kr  = tid >> 4, nc = (tid & 15) * 4;
        const int rr  = tid >> 2, c0 = tid & 3;
        for (int kk = 0; kk < 4; ++kk) {
            const int k0 = ktg * 256 + kk * 64;
            const int n0 = nt * 64;
            const float* src = W1 + ((size_t)e * DM + k0 + kr) * DF + n0 + nc;
#pragma unroll
            for (int i2 = 0; i2 < 4; ++i2) {
                const float4 v = *reinterpret_cast<const float4*>(src + (size_t)i2 * 16 * DF);
                T[nc + 0][kr + i2 * 16] = f2bf(v.x);
                T[nc + 1][kr + i2 * 16] = f2bf(v.y);
                T[nc + 2][kr + i2 * 16] = f2bf(v.z);
                T[nc + 3][kr + i2 * 16] = f2bf(v.w);
            }
            __syncthreads();
            ushort* dst = w1b + ((size_t)e * DF + n0 + rr) * DM + k0;
#pragma unroll
            for (int i2 = 0; i2 < 2; ++i2) {
                const int c = c0 + i2 * 4;
                *reinterpret_cast<uint4*>(dst + c * 8) =
                    *reinterpret_cast<const uint4*>(&T[rr][c * 8]);
            }
            __syncthreads();
        }
    }
}

// ====== fused GEMM1 [0,4096) + transpose W2 [4096,6144) ======================
// GEMM1 branch is byte-identical to R10's moe_gemm10 (85us measured): 128x128,
// BK=32 dbuf, chunk-XOR swizzle, counted vmcnt(4), XCD-chunked swizzle
// (bx&7 -> XCD; expert-per-XCD; mt fastest). trW2 blocks ride GEMM1's idle
// HBM bandwidth (GEMM1 ran at ~500 GB/s of 6300 available).
// LDS: single 33792B union -> 4 blocks/CU preserved for the GEMM branch.
__global__ __launch_bounds__(256, 4) void gemm1_trw2(
    const ushort* __restrict__ xb, const ushort* __restrict__ w1b,
    const float* __restrict__ b1, const uint32_t* __restrict__ route,
    const uint32_t* __restrict__ cnt, const uint32_t* __restrict__ offs,
    const float* __restrict__ prob, ushort* __restrict__ hout,
    const float* __restrict__ W2, ushort* __restrict__ w2b)
{
    __shared__ __attribute__((aligned(16))) char smem[33792];
    const int bx0 = blockIdx.x;
    const int tid = threadIdx.x;

    if (bx0 < 4096) {
        // -------- GEMM1 (KD=DM, ND=DF, NMT=16, NT=32) --------
        ushort* Asm = (ushort*)smem;                       // [2][128*32] 16KB
        ushort* Bsm = (ushort*)(smem + 16384);             // [2][128*32] 16KB
        uint32_t* s_route = (uint32_t*)(smem + 32768);     // 512B
        float* s_p = (float*)(smem + 33280);               // 512B

        const int cpx = (NEXP * 16 * 32) >> 3;             // 512
        const int wk  = (bx0 & 7) * cpx + (bx0 >> 3);
        const int e   = wk / (16 * 32);
        const int r   = wk % (16 * 32);
        const int nt  = r / 16;
        const int mt  = r % 16;
        const uint32_t cntE = cnt[e];
        const int m0 = mt * 128;
        if ((uint32_t)m0 >= cntE) return;
        const uint32_t hb = offs[e];
        const int n0 = nt * 128;
        const int niter = DM / 32;

        if (tid < 128) {
            const uint32_t idx = (uint32_t)(m0 + tid);
            const uint32_t s = (idx < cntE) ? route[e * T_TOKENS + idx] : 0u;
            s_route[tid] = s;
            s_p[tid] = prob[s];
        }
        __syncthreads();

        const int w = tid >> 6, l = tid & 63;
        const ushort* asrc[2];
        const ushort* bsrc[2];
#pragma unroll
        for (int i = 0; i < 2; ++i) {
            const int chunk = (w * 2 + i) * 64 + l;
            const int row = chunk >> 2;
            const int c   = chunk & 3;
            const int cs  = c ^ ((row >> 1) & 3);
            const size_t arow = (size_t)(s_route[row] >> 1);
            asrc[i] = xb + arow * DM + cs * 8;
            bsrc[i] = w1b + ((size_t)e * DF + n0 + row) * DM + cs * 8;
        }

        f32x4 acc[4][4];
#pragma unroll
        for (int i = 0; i < 4; ++i)
#pragma unroll
            for (int j = 0; j < 4; ++j) acc[i][j] = (f32x4){0.f, 0.f, 0.f, 0.f};

        const int q = l & 15, g = l >> 4;
        const int wm = w >> 1, wn = w & 1;
        int aoff[4], boff[4];
#pragma unroll
        for (int mi = 0; mi < 4; ++mi) {
            int row = wm * 64 + mi * 16 + q;
            aoff[mi] = row * 64 + (g ^ ((row >> 1) & 3)) * 16;
            row = wn * 64 + mi * 16 + q;
            boff[mi] = row * 64 + (g ^ ((row >> 1) & 3)) * 16;
        }

#pragma unroll
        for (int i = 0; i < 2; ++i) gload16(asrc[i], Asm + (w * 2 + i) * 512);
#pragma unroll
        for (int i = 0; i < 2; ++i) gload16(bsrc[i], Bsm + (w * 2 + i) * 512);

        int cur = 0;
        for (int t = 0; t < niter; ++t) {
            if (t + 1 < niter) {
                ushort* ad = Asm + (cur ^ 1) * (128 * 32) + (w * 2) * 512;
                ushort* bd = Bsm + (cur ^ 1) * (128 * 32) + (w * 2) * 512;
                const int k1 = (t + 1) * 32;
#pragma unroll
                for (int i = 0; i < 2; ++i) gload16(asrc[i] + k1, ad + i * 512);
#pragma unroll
                for (int i = 0; i < 2; ++i) gload16(bsrc[i] + k1, bd + i * 512);
                asm volatile("s_waitcnt vmcnt(4)" ::: "memory");
            } else {
                asm volatile("s_waitcnt vmcnt(0)" ::: "memory");
            }
            __builtin_amdgcn_s_barrier();
            __builtin_amdgcn_sched_barrier(0);

            const char* Ab = (const char*)(Asm + cur * (128 * 32));
            const char* Bb = (const char*)(Bsm + cur * (128 * 32));
            bf16x8 af[4], bv[4];
#pragma unroll
            for (int mi = 0; mi < 4; ++mi)
                af[mi] = *reinterpret_cast<const bf16x8*>(Ab + aoff[mi]);
#pragma unroll
            for (int ni = 0; ni < 4; ++ni)
                bv[ni] = *reinterpret_cast<const bf16x8*>(Bb + boff[ni]);
            __builtin_amdgcn_s_setprio(1);
#pragma unroll
            for (int mi = 0; mi < 4; ++mi)
#pragma unroll
                for (int ni = 0; ni < 4; ++ni)
                    acc[mi][ni] = __builtin_amdgcn_mfma_f32_16x16x32_bf16(
                        af[mi], bv[ni], acc[mi][ni], 0, 0, 0);
            __builtin_amdgcn_s_setprio(0);
            __builtin_amdgcn_s_barrier();
            cur ^= 1;
        }

#pragma unroll
        for (int mi = 0; mi < 4; ++mi) {
#pragma unroll
            for (int ni = 0; ni < 4; ++ni) {
                const int gcol = n0 + wn * 64 + ni * 16 + q;
#pragma unroll
                for (int j = 0; j < 4; ++j) {
                    const int row = wm * 64 + mi * 16 + g * 4 + j;
                    if ((uint32_t)(m0 + row) < cntE) {
                        const size_t grow = (size_t)(hb + m0 + row);
                        float v = acc[mi][ni][j] + b1[e * DF + gcol];
                        v = fmaxf(v, 0.f) * s_p[row];
                        hout[grow * DF + gcol] = f2bf(v);
                    }
                }
            }
        }
    } else {
        // -------- W2 [E][DF][DM] f32 -> w2b [E][DM][DF] bf16 --------
        ushort (*T)[80] = reinterpret_cast<ushort(*)[80]>(smem);
        const int rel = bx0 - 4096;       // 0..2047
        const int e   = rel >> 8;         // 256 blocks/expert
        const int r   = rel & 255;
        const int nt  = r & 15;           // DM/64 = 16 n-tiles
        const int ktg = r >> 4;           // DF/256 = 16 k-groups
        const int kr  = tid >> 4, nc = (tid & 15) * 4;
        const int rr  = tid >> 2, c0 = tid & 3;
        for (int kk = 0; kk < 4; ++kk) {
            const int k0 = ktg * 256 + kk * 64;
            const int n0 = nt * 64;
            const float* src = W2 + ((size_t)e * DF + k0 + kr) * DM + n0 + nc;
#pragma unroll
            for (int i2 = 0; i2 < 4; ++i2) {
                const float4 v = *reinterpret_cast<const float4*>(src + (size_t)i2 * 16 * DM);
                T[nc + 0][kr + i2 * 16] = f2bf(v.x);
                T[nc + 1][kr + i2 * 16] = f2bf(v.y);
                T[nc + 2][kr + i2 * 16] = f2bf(v.z);
                T[nc + 3][kr + i2 * 16] = f2bf(v.w);
            }
            __syncthreads();
            ushort* dst = w2b + ((size_t)e * DM + n0 + rr) * DF + k0;
#pragma unroll
            for (int i2 = 0; i2 < 2; ++i2) {
                const int c = c0 + i2 * 4;
                *reinterpret_cast<uint4*>(dst + c * 8) =
                    *reinterpret_cast<const uint4*>(&T[rr][c * 8]);
            }
            __syncthreads();
        }
    }
}

// -------- grouped expert GEMM (R10 structure, used for GEMM2) ----------------
template<int KD, int ND, bool FIRST, int SPLIT, int NMT, int NT>
__global__ __launch_bounds__(256, 4) void moe_gemm10(
    const ushort* __restrict__ Abuf,
    const ushort* __restrict__ Wb,
    const float* __restrict__ bias,
    const uint32_t* __restrict__ route,
    const uint32_t* __restrict__ cnt,
    const uint32_t* __restrict__ offs,
    const float* __restrict__ prob,
    ushort* __restrict__ hout,
    float* __restrict__ yout)
{
    const int bx0 = blockIdx.x;
    const int cpx = (NEXP * NMT * NT) >> 3;
    const int wk  = (bx0 & 7) * cpx + (bx0 >> 3);
    const int e   = wk / (NMT * NT);
    const int r   = wk % (NMT * NT);
    const int nt  = r / NMT;
    const int mt  = r % NMT;
    const uint32_t cntE = cnt[e];
    const int m0 = mt * 128;
    if ((uint32_t)m0 >= cntE) return;
    const uint32_t hb = offs[e];
    const int n0 = nt * 128;
    const int z  = (SPLIT > 1) ? (int)blockIdx.z : 0;
    const int kbeg = z * (KD / SPLIT);
    const int niter = (KD / SPLIT) / 32;

    __shared__ ushort As[2][128 * 32];
    __shared__ ushort Bs[2][128 * 32];
    __shared__ uint32_t s_route[128];
    __shared__ float s_p[128];

    const int tid = threadIdx.x;
    if (FIRST) {
        if (tid < 128) {
            const uint32_t idx = (uint32_t)(m0 + tid);
            const uint32_t s = (idx < cntE) ? route[e * T_TOKENS + idx] : 0u;
            s_route[tid] = s;
            s_p[tid] = prob[s];
        }
        __syncthreads();
    }

    const int w = tid >> 6, l = tid & 63;
    const ushort* asrc[2];
    const ushort* bsrc[2];
#pragma unroll
    for (int i = 0; i < 2; ++i) {
        const int chunk = (w * 2 + i) * 64 + l;
        const int row = chunk >> 2;
        const int c   = chunk & 3;
        const int cs  = c ^ ((row >> 1) & 3);
        size_t arow;
        if (FIRST) arow = (size_t)(s_route[row] >> 1);
        else       arow = (size_t)(hb + m0 + row);
        asrc[i] = Abuf + arow * KD + cs * 8 + kbeg;
        bsrc[i] = Wb + ((size_t)e * ND + n0 + row) * KD + cs * 8 + kbeg;
    }

    f32x4 acc[4][4];
#pragma unroll
    for (int i = 0; i < 4; ++i)
#pragma unroll
        for (int j = 0; j < 4; ++j) acc[i][j] = (f32x4){0.f, 0.f, 0.f, 0.f};

    const int q = l & 15, g = l >> 4;
    const int wm = w >> 1, wn = w & 1;
    int aoff[4], boff[4];
#pragma unroll
    for (int mi = 0; mi < 4; ++mi) {
        int row = wm * 64 + mi * 16 + q;
        aoff[mi] = row * 64 + (g ^ ((row >> 1) & 3)) * 16;
        row = wn * 64 + mi * 16 + q;
        boff[mi] = row * 64 + (g ^ ((row >> 1) & 3)) * 16;
    }

    ushort* const abase0 = &As[0][0];
    ushort* const bbase0 = &Bs[0][0];

#pragma unroll
    for (int i = 0; i < 2; ++i) gload16(asrc[i], abase0 + (w * 2 + i) * 512);
#pragma unroll
    for (int i = 0; i < 2; ++i) gload16(bsrc[i], bbase0 + (w * 2 + i) * 512);

    int cur = 0;
    for (int t = 0; t < niter; ++t) {
        if (t + 1 < niter) {
            ushort* ad = abase0 + (cur ^ 1) * (128 * 32) + (w * 2) * 512;
            ushort* bd = bbase0 + (cur ^ 1) * (128 * 32) + (w * 2) * 512;
            const int k1 = (t + 1) * 32;
#pragma unroll
            for (int i = 0; i < 2; ++i) gload16(asrc[i] + k1, ad + i * 512);
#pragma unroll
            for (int i = 0; i < 2; ++i) gload16(bsrc[i] + k1, bd + i * 512);
            asm volatile("s_waitcnt vmcnt(4)" ::: "memory");
        } else {
            asm volatile("s_waitcnt vmcnt(0)" ::: "memory");
        }
        __builtin_amdgcn_s_barrier();
        __builtin_amdgcn_sched_barrier(0);

        const char* Ab = (const char*)(abase0 + cur * (128 * 32));
        const char* Bb = (const char*)(bbase0 + cur * (128 * 32));
        bf16x8 af[4], bv[4];
#pragma unroll
        for (int mi = 0; mi < 4; ++mi)
            af[mi] = *reinterpret_cast<const bf16x8*>(Ab + aoff[mi]);
#pragma unroll
        for (int ni = 0; ni < 4; ++ni)
            bv[ni] = *reinterpret_cast<const bf16x8*>(Bb + boff[ni]);
        __builtin_amdgcn_s_setprio(1);
#pragma unroll
        for (int mi = 0; mi < 4; ++mi)
#pragma unroll
            for (int ni = 0; ni < 4; ++ni)
                acc[mi][ni] = __builtin_amdgcn_mfma_f32_16x16x32_bf16(
                    af[mi], bv[ni], acc[mi][ni], 0, 0, 0);
        __builtin_amdgcn_s_setprio(0);
        __builtin_amdgcn_s_barrier();
        cur ^= 1;
    }

#pragma unroll
    for (int mi = 0; mi < 4; ++mi) {
#pragma unroll
        for (int ni = 0; ni < 4; ++ni) {
            const int gcol = n0 + wn * 64 + ni * 16 + q;
#pragma unroll
            for (int j = 0; j < 4; ++j) {
                const int row = wm * 64 + mi * 16 + g * 4 + j;
                if ((uint32_t)(m0 + row) < cntE) {
                    const size_t grow = (size_t)(hb + m0 + row);
                    if (FIRST) {
                        float v = acc[mi][ni][j] + bias[e * ND + gcol];
                        v = fmaxf(v, 0.f) * s_p[row];
                        hout[grow * ND + gcol] = f2bf(v);
                    } else {
                        yout[((size_t)z * NSLOTS + grow) * ND + gcol] = acc[mi][ni][j];
                    }
                }
            }
        }
    }
}

// ------- combine: out[t] = p0*b2[e0] + p1*b2[e1] + sum_z (yc[z][r0]+yc[z][r1])
__global__ __launch_bounds__(256) void combine5(
    const float* __restrict__ yc, const uint32_t* __restrict__ epk,
    const uint32_t* __restrict__ offs, const float* __restrict__ prob,
    const float* __restrict__ b2, float* __restrict__ out)
{
    const int gid = blockIdx.x * 256 + threadIdx.x;
    const int t = gid >> 8;
    const int dq = gid & 255;
    const uint32_t p0 = epk[2 * t], p1 = epk[2 * t + 1];
    const uint32_t e0 = p0 >> 16, e1 = p1 >> 16;
    const uint32_t r0 = offs[e0] + (p0 & 0xFFFFu);
    const uint32_t r1 = offs[e1] + (p1 & 0xFFFFu);
    const float w0 = prob[2 * t], w1 = prob[2 * t + 1];
    const float4 bb0 = reinterpret_cast<const float4*>(b2 + (size_t)e0 * DM)[dq];
    const float4 bb1 = reinterpret_cast<const float4*>(b2 + (size_t)e1 * DM)[dq];
    float4 o = { w0 * bb0.x + w1 * bb1.x, w0 * bb0.y + w1 * bb1.y,
                 w0 * bb0.z + w1 * bb1.z, w0 * bb0.w + w1 * bb1.w };
    const float4* Y = reinterpret_cast<const float4*>(yc);
#pragma unroll
    for (int zz = 0; zz < 4; ++zz) {
        const float4 a = Y[((size_t)zz * NSLOTS + r0) * 256 + dq];
        const float4 b = Y[((size_t)zz * NSLOTS + r1) * 256 + dq];
        o.x += a.x + b.x; o.y += a.y + b.y; o.z += a.z + b.z; o.w += a.w + b.w;
    }
    reinterpret_cast<float4*>(out)[gid] = o;
}

// ================= fallback path (round-1, works in ~55 MB ws) =================
__global__ __launch_bounds__(256) void gate_route_fb(
    const float* __restrict__ x, const float* __restrict__ gw,
    const float* __restrict__ gb,
    uint32_t* __restrict__ route, uint32_t* __restrict__ cnt,
    float* __restrict__ prob)
{
    const int w = threadIdx.x >> 6;
    const int lane = threadIdx.x & 63;
    const int t = blockIdx.x * 4 + w;
    float acc[NEXP];
#pragma unroll
    for (int e = 0; e < NEXP; ++e) acc[e] = 0.f;
    const float* xr = x + (size_t)t * DM;
#pragma unroll
    for (int j = 0; j < DM / 64; ++j) {
        const int d = j * 64 + lane;
        const float xv = xr[d];
        const float* g = gw + (size_t)d * NEXP;
#pragma unroll
        for (int e = 0; e < NEXP; ++e) acc[e] += xv * g[e];
    }
#pragma unroll
    for (int e = 0; e < NEXP; ++e) {
#pragma unroll
        for (int off = 32; off > 0; off >>= 1)
            acc[e] += __shfl_xor(acc[e], off);
        acc[e] += gb[e];
    }
    if (lane == 0) {
        int e0 = 0; float v0 = acc[0];
#pragma unroll
        for (int e = 1; e < NEXP; ++e) if (acc[e] > v0) { v0 = acc[e]; e0 = e; }
        int e1 = -1; float v1 = -1e30f;
#pragma unroll
        for (int e = 0; e < NEXP; ++e) if (e != e0 && acc[e] > v1) { v1 = acc[e]; e1 = e; }
        const float ex = expf(v1 - v0);
        const float inv = 1.f / (1.f + ex);
        prob[t * 2 + 0] = inv;
        prob[t * 2 + 1] = ex * inv;
        uint32_t pos = atomicAdd(&cnt[e0], 1u);
        route[e0 * T_TOKENS + pos] = (uint32_t)(t * 2);
        pos = atomicAdd(&cnt[e1], 1u);
        route[e1 * T_TOKENS + pos] = (uint32_t)(t * 2 + 1);
    }
}

__global__ __launch_bounds__(256) void convert_x_fb(const float* __restrict__ x,
                                                    ushort* __restrict__ xb)
{
    const int i = (blockIdx.x * 256 + threadIdx.x) * 4;
    const float4 v = *reinterpret_cast<const float4*>(x + i);
    ushort4 o;
    o.x = f2bf(v.x); o.y = f2bf(v.y); o.z = f2bf(v.z); o.w = f2bf(v.w);
    *reinterpret_cast<ushort4*>(xb + i) = o;
}

template<int KD, int ND, bool FIRST>
__global__ __launch_bounds__(256) void moe_gemm_v1(
    const ushort* __restrict__ Abuf, const float* __restrict__ W,
    const float* __restrict__ bias, const uint32_t* __restrict__ route,
    const uint32_t* __restrict__ cnt, const float* __restrict__ prob,
    ushort* __restrict__ hout, float* __restrict__ yout)
{
    const int e = blockIdx.x >> 4;
    const int mt = blockIdx.x & 15;
    const uint32_t cntE = cnt[e];
    const int m0 = mt * 128;
    if ((uint32_t)m0 >= cntE) return;
    const int n0 = blockIdx.y * 128;
    const int tid = threadIdx.x;
    __shared__ ushort Asm[128][40];
    __shared__ ushort Bsm[128][40];
    __shared__ uint32_t s_route[128];
    if (tid < 128) {
        const uint32_t idx = (uint32_t)(m0 + tid);
        s_route[tid] = (idx < cntE) ? route[e * T_TOKENS + idx] : 0xFFFFFFFFu;
    }
    __syncthreads();
    const int ar = tid >> 1, ah = tid & 1;
    const uint32_t s_a = s_route[ar];
    size_t arow = 0;
    if (s_a != 0xFFFFFFFFu) arow = FIRST ? (size_t)(s_a >> 1) : (size_t)s_a;
    const ushort* asrc = Abuf + arow * KD + ah * 16;
    const int c4 = tid & 31, kq = tid >> 5;
    const float* wbase = W + (size_t)e * KD * ND + (size_t)n0 + (size_t)c4 * 4;
    f32x4 acc[4][4];
#pragma unroll
    for (int i = 0; i < 4; ++i)
#pragma unroll
        for (int j = 0; j < 4; ++j) acc[i][j] = (f32x4){0.f, 0.f, 0.f, 0.f};
    const int lane = tid & 63, wv = tid >> 6;
    const int wm = wv >> 1, wn = wv & 1;
    const int q = lane & 15, g = lane >> 4;
    for (int k0 = 0; k0 < KD; k0 += 32) {
        {
            const uint4* src = reinterpret_cast<const uint4*>(asrc + k0);
            const uint4 v0 = src[0];
            const uint4 v1 = src[1];
            *reinterpret_cast<uint4*>(&Asm[ar][ah * 16]) = v0;
            *reinterpret_cast<uint4*>(&Asm[ar][ah * 16 + 8]) = v1;
        }
        {
            ushort vals[4][4];
#pragma unroll
            for (int r = 0; r < 4; ++r) {
                const float4 v = *reinterpret_cast<const float4*>(
                    wbase + (size_t)(k0 + kq * 4 + r) * ND);
                vals[r][0] = f2bf(v.x); vals[r][1] = f2bf(v.y);
                vals[r][2] = f2bf(v.z); vals[r][3] = f2bf(v.w);
            }
#pragma unroll
            for (int c = 0; c < 4; ++c) {
                const ushort4 o = { vals[0][c], vals[1][c], vals[2][c], vals[3][c] };
                *reinterpret_cast<ushort4*>(&Bsm[c4 * 4 + c][kq * 4]) = o;
            }
        }
        __syncthreads();
        bf16x8 af[4], bfr[4];
#pragma unroll
        for (int mi = 0; mi < 4; ++mi)
            af[mi] = *reinterpret_cast<const bf16x8*>(&Asm[wm * 64 + mi * 16 + q][g * 8]);
#pragma unroll
        for (int ni = 0; ni < 4; ++ni)
            bfr[ni] = *reinterpret_cast<const bf16x8*>(&Bsm[wn * 64 + ni * 16 + q][g * 8]);
#pragma unroll
        for (int mi = 0; mi < 4; ++mi)
#pragma unroll
            for (int ni = 0; ni < 4; ++ni)
                acc[mi][ni] = __builtin_amdgcn_mfma_f32_16x16x32_bf16(
                    af[mi], bfr[ni], acc[mi][ni], 0, 0, 0);
        __syncthreads();
    }
#pragma unroll
    for (int mi = 0; mi < 4; ++mi) {
#pragma unroll
        for (int ni = 0; ni < 4; ++ni) {
            const int gcol = n0 + wn * 64 + ni * 16 + q;
#pragma unroll
            for (int j = 0; j < 4; ++j) {
                const int row = wm * 64 + mi * 16 + g * 4 + j;
                if ((uint32_t)(m0 + row) < cntE) {
                    const uint32_t s = s_route[row];
                    float v = acc[mi][ni][j] + bias[e * ND + gcol];
                    if (FIRST) {
                        v = fmaxf(v, 0.f);
                        hout[(size_t)s * ND + gcol] = f2bf(v);
                    } else {
                        yout[(size_t)s * ND + gcol] = v * prob[s];
                    }
                }
            }
        }
    }
}

__global__ __launch_bounds__(256) void combine1(const float* __restrict__ yc,
                                                float* __restrict__ out)
{
    const int gid = blockIdx.x * 256 + threadIdx.x;
    const int t = gid >> 8;
    const int dq = gid & 255;
    const float4 va = reinterpret_cast<const float4*>(yc)[(size_t)(2 * t) * 256 + dq];
    const float4 vb = reinterpret_cast<const float4*>(yc)[(size_t)(2 * t + 1) * 256 + dq];
    const float4 o = { va.x + vb.x, va.y + vb.y, va.z + vb.z, va.w + vb.w };
    reinterpret_cast<float4*>(out)[gid] = o;
}

// ---------------- launch ----------------
extern "C" void kernel_launch(void* const* d_in, const int* in_sizes, int n_in,
                              void* d_out, int out_size, void* d_ws, size_t ws_size,
                              hipStream_t stream)
{
    const float* x  = (const float*)d_in[0];
    const float* gw = (const float*)d_in[1];
    const float* gb = (const float*)d_in[2];
    const float* W1 = (const float*)d_in[3];
    const float* b1 = (const float*)d_in[4];
    const float* W2 = (const float*)d_in[5];
    const float* b2 = (const float*)d_in[6];
    float* out = (float*)d_out;
    char* ws = (char*)d_ws;

    // ---- big layout (~168 MB; yc aliases w1b which is dead after GEMM1) ----
    const size_t OFF_XB    = 0;                        // 4 MiB
    const size_t OFF_H     = 4194304;                  // (NSLOTS+128)*4096*2
    const size_t OFF_ROUTE = 38797312;                 // 64 KiB
    const size_t OFF_CNT   = 38862848;                 // 64 B
    const size_t OFF_OFFS  = 38862912;                 // 64 B
    const size_t OFF_PROB  = 38862976;                 // 16 KiB
    const size_t OFF_EPK   = 38879360;                 // 16 KiB
    const size_t OFF_W1B   = 41943040;                 // 64 MiB (aliased by yc)
    const size_t OFF_W2B   = 109051904;                // 64 MiB
    const size_t OFF_YC    = OFF_W1B;                  // 64 MiB (4 z-splits)
    const size_t NEED      = 176160768ull;

    if (ws_size >= NEED) {
        ushort*   xb    = (ushort*)(ws + OFF_XB);
        ushort*   h     = (ushort*)(ws + OFF_H);
        float*    yc    = (float*)(ws + OFF_YC);
        uint32_t* route = (uint32_t*)(ws + OFF_ROUTE);
        uint32_t* cnt   = (uint32_t*)(ws + OFF_CNT);
        uint32_t* offs  = (uint32_t*)(ws + OFF_OFFS);
        float*    prob  = (float*)(ws + OFF_PROB);
        uint32_t* epk   = (uint32_t*)(ws + OFF_EPK);
        ushort*   w1b   = (ushort*)(ws + OFF_W1B);
        ushort*   w2b   = (ushort*)(ws + OFF_W2B);

        hipLaunchKernelGGL(init_cnt, dim3(1), dim3(64), 0, stream, cnt);
        // fused prep: gate_route (512) | convert_x (2048) | trW1 (2048)
        hipLaunchKernelGGL(prep_kernel, dim3(4608), dim3(256), 0, stream,
                           x, gw, gb, W1, route, cnt, prob, epk, xb, w1b);
        hipLaunchKernelGGL(prefix_offs, dim3(1), dim3(64), 0, stream, cnt, offs);
        // fused: GEMM1 (4096, XCD-swizzled) | trW2 (2048)
        hipLaunchKernelGGL(gemm1_trw2, dim3(4096 + 2048), dim3(256), 0, stream,
                           xb, w1b, b1, route, cnt, offs, prob, h, W2, w2b);
        // GEMM2: 128x128, split-K=4, NMT=16, NT=8; yc aliases w1b (dead now)
        hipLaunchKernelGGL((moe_gemm10<DF, DM, false, 4, 16, 8>),
                           dim3(NEXP * 16 * 8, 1, 4), dim3(256), 0, stream,
                           h, w2b, (const float*)nullptr, route, cnt, offs,
                           (const float*)nullptr, (ushort*)nullptr, yc);
        hipLaunchKernelGGL(combine5, dim3(T_TOKENS * DM / 1024), dim3(256), 0, stream,
                           yc, epk, offs, prob, b2, out);
    } else {
        // ---- fallback: round-1 layout (~55 MB) ----
        const size_t F_XB = 0, F_H = 4194304, F_YC = 37748736;
        const size_t F_ROUTE = 54525952, F_CNT = 54591488, F_PROB = 54591552;
        ushort*   xb    = (ushort*)(ws + F_XB);
        ushort*   h     = (ushort*)(ws + F_H);
        float*    yc    = (float*)(ws + F_YC);
        uint32_t* route = (uint32_t*)(ws + F_ROUTE);
        uint32_t* cnt   = (uint32_t*)(ws + F_CNT);
        float*    prob  = (float*)(ws + F_PROB);

        hipLaunchKernelGGL(init_cnt, dim3(1), dim3(64), 0, stream, cnt);
        hipLaunchKernelGGL(gate_route_fb, dim3(T_TOKENS / 4), dim3(256), 0, stream,
                           x, gw, gb, route, cnt, prob);
        hipLaunchKernelGGL(convert_x_fb, dim3(T_TOKENS * DM / 1024), dim3(256), 0, stream, x, xb);
        hipLaunchKernelGGL((moe_gemm_v1<DM, DF, true>), dim3(NEXP * 16, DF / 128),
                           dim3(256), 0, stream, xb, W1, b1, route, cnt, prob,
                           h, (float*)nullptr);
        hipLaunchKernelGGL((moe_gemm_v1<DF, DM, false>), dim3(NEXP * 16, DM / 128),
                           dim3(256), 0, stream, h, W2, b2, route, cnt, prob,
                           (ushort*)nullptr, yc);
        hipLaunchKernelGGL(combine1, dim3(T_TOKENS * DM / 1024), dim3(256), 0, stream, yc, out);
    }
}